// Round 1
// baseline (456.033 us; speedup 1.0000x reference)
//
#include <hip/hip_runtime.h>

// Problem: B=4096, N=64, L=256, E=256, all fp32.
// d_in: 0=agent[B,L] 1=opp[B,N,L] 2=hard[B,N] 3=Ws[E,L] 4=Wt[E,L] 5=Wc[E,L]
// d_out: result[B,E] (1048576 f32) then scores[B,N] (262144 f32)
//
// Algebra: scores[b,n] = opp[b,n,:] @ M @ agent[b,:],  M[l,l'] = sum_e Wt[e,l]*Ws[e,l']
//          result[b,e] = sum_l Wc[e,l] * v[b,l],       v[b,l] = sum_n s[b,n]*opp[b,n,l]
// => opp (256 MB) is streamed exactly once (LDS-staged, reused for scores and v).

#define Bsz 4096
#define Nn  64
#define Ll  256
#define Ee  256

// ---------------- prep: MT[l'][l] = sum_e Ws[e,l']*Wt[e,l] ; WcT[l][e] = Wc[e,l]
__global__ __launch_bounds__(256) void prep_kernel(
    const float* __restrict__ Ws, const float* __restrict__ Wt,
    const float* __restrict__ Wc, float* __restrict__ MT, float* __restrict__ WcT) {
  int col = threadIdx.x;
  int row = blockIdx.x;
  if (row < 256) {
    float acc = 0.f;
    for (int e = 0; e < 256; ++e)
      acc = fmaf(Ws[e * 256 + row], Wt[e * 256 + col], acc);   // Ws: block-uniform addr (scalar), Wt: coalesced
    MT[row * 256 + col] = acc;
  } else {
    int l = row - 256;
    WcT[l * 256 + col] = Wc[col * 256 + l];
  }
}

// ---------------- rowmat: out[b,j] = sum_k in[b,k] * W[k*256 + j]
// block: 16 rows of `in` staged in LDS; 256 threads; thread = (j-lane = tid&63 within
// blockIdx.y*64.., 4 local rows). grid (B/16, 256/64) = (256,4).
__global__ __launch_bounds__(256) void rowmat_kernel(
    const float* __restrict__ in, const float* __restrict__ W, float* __restrict__ out) {
  __shared__ float v_s[16 * 256];   // 16 KB
  const int tid = threadIdx.x;
  const int b0 = blockIdx.x * 16;
  const int j  = blockIdx.y * 64 + (tid & 63);
  const int g  = (tid >> 6) * 4;    // 4 local rows per thread

  const float4* in4 = (const float4*)(in + (size_t)b0 * 256);
  float4* s4 = (float4*)v_s;
#pragma unroll
  for (int i = 0; i < 4; ++i) s4[i * 256 + tid] = in4[i * 256 + tid];
  __syncthreads();

  float acc[4] = {0.f, 0.f, 0.f, 0.f};
  for (int k4 = 0; k4 < 64; ++k4) {
    // 4 weight scalars, coalesced across the 64 lanes of each wave (L1-hit for waves 1-3)
    const float w0 = W[(k4 * 4 + 0) * 256 + j];
    const float w1 = W[(k4 * 4 + 1) * 256 + j];
    const float w2 = W[(k4 * 4 + 2) * 256 + j];
    const float w3 = W[(k4 * 4 + 3) * 256 + j];
#pragma unroll
    for (int i = 0; i < 4; ++i) {
      const float4 vv = ((const float4*)(v_s + (g + i) * 256))[k4];  // wave-broadcast b128
      acc[i] = fmaf(vv.x, w0, fmaf(vv.y, w1, fmaf(vv.z, w2, fmaf(vv.w, w3, acc[i]))));
    }
  }
#pragma unroll
  for (int i = 0; i < 4; ++i) out[(size_t)(b0 + g + i) * 256 + j] = acc[i];
}

// ---------------- fused per-b: stage opp[b] once -> scores -> softmax*hard -> v
__global__ __launch_bounds__(256, 2) void fused_kernel(
    const float* __restrict__ opp, const float* __restrict__ T,
    const float* __restrict__ hard, float* __restrict__ scores_out,
    float* __restrict__ V) {
  __shared__ float opp_s[Nn * Ll];  // 64 KB
  __shared__ float t_s[Ll];
  __shared__ float sraw[Nn];
  __shared__ float sfin[Nn];

  const int b = blockIdx.x;
  const int tid = threadIdx.x;
  const int lane = tid & 63;
  const int wave = tid >> 6;

  // stage opp[b] (16384 floats = 4096 float4), fully coalesced
  const float4* o4 = (const float4*)(opp + (size_t)b * (Nn * Ll));
  float4* os4 = (float4*)opp_s;
#pragma unroll
  for (int i = 0; i < 16; ++i) os4[i * 256 + tid] = o4[i * 256 + tid];
  t_s[tid] = T[(size_t)b * Ll + tid];
  __syncthreads();

  // scores: wave w handles n = w*16 .. w*16+15; 64-lane dot of opp_s[n,:] with t
  const float4 tv = ((const float4*)t_s)[lane];
  for (int jj = 0; jj < 16; ++jj) {
    const int n = wave * 16 + jj;
    const float4 ov = ((const float4*)(opp_s + n * Ll))[lane];
    float p = ov.x * tv.x + ov.y * tv.y + ov.z * tv.z + ov.w * tv.w;
#pragma unroll
    for (int off = 32; off; off >>= 1) p += __shfl_down(p, off, 64);
    if (lane == 0) sraw[n] = p;
  }
  __syncthreads();

  // softmax over n (64 values) * hard_attention, one wave
  if (tid < 64) {
    const float x = sraw[tid];
    float m = x;
#pragma unroll
    for (int off = 32; off; off >>= 1) m = fmaxf(m, __shfl_xor(m, off, 64));
    const float e = __expf(x - m);
    float s = e;
#pragma unroll
    for (int off = 32; off; off >>= 1) s += __shfl_xor(s, off, 64);
    const float val = e / s * hard[(size_t)b * Nn + tid];
    sfin[tid] = val;
    scores_out[(size_t)b * Nn + tid] = val;
  }
  __syncthreads();

  // v[b,l] = sum_n s[n] * opp[b,n,l]; thread l = tid. opp_s reads: lanes hit
  // consecutive banks (2 lanes/bank = free), sfin[n] is a broadcast.
  float acc = 0.f;
#pragma unroll
  for (int n = 0; n < Nn; ++n) acc = fmaf(sfin[n], opp_s[n * Ll + tid], acc);
  V[(size_t)b * Ll + tid] = acc;
}

extern "C" void kernel_launch(void* const* d_in, const int* in_sizes, int n_in,
                              void* d_out, int out_size, void* d_ws, size_t ws_size,
                              hipStream_t stream) {
  const float* agent = (const float*)d_in[0];
  const float* opp   = (const float*)d_in[1];
  const float* hard  = (const float*)d_in[2];
  const float* Ws    = (const float*)d_in[3];
  const float* Wt    = (const float*)d_in[4];
  const float* Wc    = (const float*)d_in[5];

  float* out = (float*)d_out;               // result [B,E]
  float* scores_out = out + (size_t)Bsz * Ee;  // scores [B,N]

  float* ws  = (float*)d_ws;
  float* MT  = ws;                           // 65536
  float* WcT = MT + 65536;                   // 65536
  float* T   = WcT + 65536;                  // B*L = 1048576
  float* V   = T + (size_t)Bsz * Ll;         // B*L = 1048576

  prep_kernel<<<512, 256, 0, stream>>>(Ws, Wt, Wc, MT, WcT);
  rowmat_kernel<<<dim3(Bsz / 16, 4), 256, 0, stream>>>(agent, MT, T);   // T = agent @ M.T
  fused_kernel<<<Bsz, 256, 0, stream>>>(opp, T, hard, scores_out, V);
  rowmat_kernel<<<dim3(Bsz / 16, 4), 256, 0, stream>>>(V, WcT, out);    // result = V @ Wc.T
}

// Round 2
// 454.248 us; speedup vs baseline: 1.0039x; 1.0039x over previous
//
#include <hip/hip_runtime.h>

// Problem: B=4096, N=64, L=256, E=256, all fp32.
// d_in: 0=agent[B,L] 1=opp[B,N,L] 2=hard[B,N] 3=Ws[E,L] 4=Wt[E,L] 5=Wc[E,L]
// d_out: result[B,E] (1048576 f32) then scores[B,N] (262144 f32)
//
// Algebra: scores[b,n] = opp[b,n,:] @ M @ agent[b,:],  M[l,l'] = sum_e Wt[e,l]*Ws[e,l']
//          result[b,e] = sum_l Wc[e,l] * v[b,l],       v[b,l] = sum_n s[b,n]*opp[b,n,l]
// => opp (256 MB) is streamed exactly once (LDS-staged via global_load_lds DMA,
//    reused for scores and v). Compulsory traffic ~274 MB => ~44 us roofline.

#define Bsz 4096
#define Nn  64
#define Ll  256
#define Ee  256

// Direct HBM->LDS DMA, 16 B per lane. LDS dest must be wave-uniform base;
// HW scatters lane i at base + i*16.
__device__ __forceinline__ void gload_lds16(const float4* g, float4* lds_base) {
  __builtin_amdgcn_global_load_lds(
      (const __attribute__((address_space(1))) unsigned int*)g,
      (__attribute__((address_space(3))) unsigned int*)lds_base,
      16, 0, 0);
}

// ---------------- prep: MT[l'][l] = sum_e Ws[e,l']*Wt[e,l] ; WcT[l][e] = Wc[e,l]
__global__ __launch_bounds__(256) void prep_kernel(
    const float* __restrict__ Ws, const float* __restrict__ Wt,
    const float* __restrict__ Wc, float* __restrict__ MT, float* __restrict__ WcT) {
  int col = threadIdx.x;
  int row = blockIdx.x;
  if (row < 256) {
    float acc = 0.f;
    for (int e = 0; e < 256; ++e)
      acc = fmaf(Ws[e * 256 + row], Wt[e * 256 + col], acc);  // Ws uniform/blk, Wt coalesced
    MT[row * 256 + col] = acc;
  } else {
    int l = row - 256;
    WcT[l * 256 + col] = Wc[col * 256 + l];
  }
}

// ---------------- rowmat: out[b,j] = sum_k in[b,k] * W[k*256 + j]
// 16 rows of `in` staged in LDS; 256 threads; grid (B/16, 4).
__global__ __launch_bounds__(256) void rowmat_kernel(
    const float* __restrict__ in, const float* __restrict__ W, float* __restrict__ out) {
  __shared__ float v_s[16 * 256];  // 16 KB
  const int tid = threadIdx.x;
  const int b0 = blockIdx.x * 16;
  const int j  = blockIdx.y * 64 + (tid & 63);
  const int g  = (tid >> 6) * 4;

  const float4* in4 = (const float4*)(in + (size_t)b0 * 256);
  float4* s4 = (float4*)v_s;
#pragma unroll
  for (int i = 0; i < 4; ++i) s4[i * 256 + tid] = in4[i * 256 + tid];
  __syncthreads();

  float acc[4] = {0.f, 0.f, 0.f, 0.f};
  for (int k4 = 0; k4 < 64; ++k4) {
    const float w0 = W[(k4 * 4 + 0) * 256 + j];
    const float w1 = W[(k4 * 4 + 1) * 256 + j];
    const float w2 = W[(k4 * 4 + 2) * 256 + j];
    const float w3 = W[(k4 * 4 + 3) * 256 + j];
#pragma unroll
    for (int i = 0; i < 4; ++i) {
      const float4 vv = ((const float4*)(v_s + (g + i) * 256))[k4];
      acc[i] = fmaf(vv.x, w0, fmaf(vv.y, w1, fmaf(vv.z, w2, fmaf(vv.w, w3, acc[i]))));
    }
  }
#pragma unroll
  for (int i = 0; i < 4; ++i) out[(size_t)(b0 + g + i) * 256 + j] = acc[i];
}

// ---------------- fused per-b: DMA-stage opp[b] -> scores -> softmax*hard -> v
__global__ __launch_bounds__(256, 2) void fused_kernel(
    const float* __restrict__ opp, const float* __restrict__ T,
    const float* __restrict__ hard, float* __restrict__ scores_out,
    float* __restrict__ V) {
  __shared__ float opp_s[Nn * Ll];  // 64 KB
  __shared__ float t_s[Ll];
  __shared__ float sraw[Nn];
  __shared__ float sfin[Nn];

  const int b = blockIdx.x;
  const int tid = threadIdx.x;
  const int lane = tid & 63;
  const int wave = tid >> 6;

  // DMA stage: wave w fills opp_s float4s [i*256 + w*64 .. +64) per iter.
  // gptr per lane; LDS base wave-uniform; HW places lane at base + lane*16.
  const float4* o4 = (const float4*)(opp + (size_t)b * (Nn * Ll));
  float4* os4 = (float4*)opp_s;
#pragma unroll
  for (int i = 0; i < 16; ++i)
    gload_lds16(o4 + i * 256 + wave * 64 + lane, os4 + i * 256 + wave * 64);
  t_s[tid] = T[(size_t)b * Ll + tid];
  __syncthreads();  // drains vmcnt + lgkmcnt

  // scores: wave w handles n = w*16..w*16+15; 64-lane dot over l.
  const float4 tv = ((const float4*)t_s)[lane];
  for (int jj = 0; jj < 16; ++jj) {
    const int n = wave * 16 + jj;
    const float4 ov = ((const float4*)(opp_s + n * Ll))[lane];
    float p = ov.x * tv.x + ov.y * tv.y + ov.z * tv.z + ov.w * tv.w;
#pragma unroll
    for (int off = 32; off; off >>= 1) p += __shfl_down(p, off, 64);
    if (lane == 0) sraw[n] = p;
  }
  __syncthreads();

  // softmax over n (64 values) * hard_attention, one wave
  if (tid < 64) {
    const float x = sraw[tid];
    float m = x;
#pragma unroll
    for (int off = 32; off; off >>= 1) m = fmaxf(m, __shfl_xor(m, off, 64));
    const float e = __expf(x - m);
    float s = e;
#pragma unroll
    for (int off = 32; off; off >>= 1) s += __shfl_xor(s, off, 64);
    const float val = e / s * hard[(size_t)b * Nn + tid];
    sfin[tid] = val;
    scores_out[(size_t)b * Nn + tid] = val;
  }
  __syncthreads();

  // v[b,l] = sum_n s[n]*opp[b,n,l], vectorized: thread quarter q handles
  // n in [16q,16q+16), 4 l's at l0 = (tid&63)*4 via ds_read_b128.
  const int q = wave;
  const int l0 = (tid & 63) * 4;
  float4 acc = {0.f, 0.f, 0.f, 0.f};
#pragma unroll
  for (int k = 0; k < 16; ++k) {
    const int n = q * 16 + k;
    const float s = sfin[n];
    const float4 ov = *(const float4*)(opp_s + n * Ll + l0);
    acc.x = fmaf(s, ov.x, acc.x);
    acc.y = fmaf(s, ov.y, acc.y);
    acc.z = fmaf(s, ov.z, acc.z);
    acc.w = fmaf(s, ov.w, acc.w);
  }
  // combine the 4 quarter-partials via LDS (reuse opp_s as scratch after sync)
  __syncthreads();
  float4* part = (float4*)opp_s;  // [4][64] float4 = 4 KB
  part[q * 64 + (tid & 63)] = acc;
  __syncthreads();
  if (tid < 64) {
    float4 r = part[tid];
    const float4 r1 = part[64 + tid];
    const float4 r2 = part[128 + tid];
    const float4 r3 = part[192 + tid];
    r.x += r1.x + r2.x + r3.x;
    r.y += r1.y + r2.y + r3.y;
    r.z += r1.z + r2.z + r3.z;
    r.w += r1.w + r2.w + r3.w;
    ((float4*)(V + (size_t)b * Ll))[tid] = r;
  }
}

extern "C" void kernel_launch(void* const* d_in, const int* in_sizes, int n_in,
                              void* d_out, int out_size, void* d_ws, size_t ws_size,
                              hipStream_t stream) {
  const float* agent = (const float*)d_in[0];
  const float* opp   = (const float*)d_in[1];
  const float* hard  = (const float*)d_in[2];
  const float* Ws    = (const float*)d_in[3];
  const float* Wt    = (const float*)d_in[4];
  const float* Wc    = (const float*)d_in[5];

  float* out = (float*)d_out;                  // result [B,E]
  float* scores_out = out + (size_t)Bsz * Ee;  // scores [B,N]

  float* ws  = (float*)d_ws;
  float* MT  = ws;                     // 65536
  float* WcT = MT + 65536;             // 65536
  float* T   = WcT + 65536;            // B*L
  float* V   = T + (size_t)Bsz * Ll;   // B*L

  prep_kernel<<<512, 256, 0, stream>>>(Ws, Wt, Wc, MT, WcT);
  rowmat_kernel<<<dim3(Bsz / 16, 4), 256, 0, stream>>>(agent, MT, T);  // T = agent @ M.T
  fused_kernel<<<Bsz, 256, 0, stream>>>(opp, T, hard, scores_out, V);
  rowmat_kernel<<<dim3(Bsz / 16, 4), 256, 0, stream>>>(V, WcT, out);   // result = V @ Wc.T
}

// Round 3
// 442.809 us; speedup vs baseline: 1.0299x; 1.0258x over previous
//
#include <hip/hip_runtime.h>

// Problem: B=4096, N=64, L=256, E=256, all fp32.
// d_in: 0=agent[B,L] 1=opp[B,N,L] 2=hard[B,N] 3=Ws[E,L] 4=Wt[E,L] 5=Wc[E,L]
// d_out: result[B,E] (1048576 f32) then scores[B,N] (262144 f32)
//
// Algebra: scores[b,n] = opp[b,n,:] @ M @ agent[b,:],  M[l,l'] = sum_e Wt[e,l]*Ws[e,l']
//          result[b,e] = sum_l Wc[e,l] * v[b,l],       v[b,l] = sum_n s[b,n]*opp[b,n,l]
// => opp (256 MB) streamed exactly once via global_load_lds DMA, reused for
//    scores and v. Compulsory traffic ~274 MB => ~44 us roofline for fused.
// Timed window also contains harness resets (1 GiB ws poison ~160 us + d_in
// restore ~90 us) -> practical floor ~320 us.

#define Bsz 4096
#define Nn  64
#define Ll  256
#define Ee  256

__device__ __forceinline__ void gload_lds16(const float4* g, float4* lds_base) {
  __builtin_amdgcn_global_load_lds(
      (const __attribute__((address_space(1))) unsigned int*)g,
      (__attribute__((address_space(3))) unsigned int*)lds_base,
      16, 0, 0);
}

// ---------------- prep: MT[l'][l] = sum_e Ws[e,l']*Wt[e,l] ; WcT[l][e] = Wc[e,l]
__global__ __launch_bounds__(256) void prep_kernel(
    const float* __restrict__ Ws, const float* __restrict__ Wt,
    const float* __restrict__ Wc, float* __restrict__ MT, float* __restrict__ WcT) {
  int col = threadIdx.x;
  int row = blockIdx.x;
  if (row < 256) {
    float acc = 0.f;
    for (int e = 0; e < 256; ++e)
      acc = fmaf(Ws[e * 256 + row], Wt[e * 256 + col], acc);  // Ws uniform/blk, Wt coalesced
    MT[row * 256 + col] = acc;
  } else {
    int l = row - 256;
    WcT[l * 256 + col] = Wc[col * 256 + l];
  }
}

// ---------------- rowmat: out[b,j] = sum_k in[b,k] * W[k*256 + j]
// Register-tiled, VALU-bound: 512 blocks x 256 thr; block = 8 rows x all 256 j.
// thread: jq = tid&63 (j = 4*jq..4*jq+3 via float4 of W), rg = tid>>6 -> 2 rows.
// Per k4: 2 broadcast ds_read_b128 (in) + 4 coalesced dwordx4 (W, L1/L2-hot)
// -> 32 FMAs. DS ~2 instr : VALU 32 FMA per iter (was 4 DS : 16 FMA).
__global__ __launch_bounds__(256) void rowmat_kernel(
    const float* __restrict__ in, const float* __restrict__ W, float* __restrict__ out) {
  __shared__ float in_s[8 * 256];  // 8 KB
  const int tid = threadIdx.x;
  const int b0 = blockIdx.x * 8;
  const int jq = tid & 63;
  const int r0 = (tid >> 6) * 2;

  const float4* in4 = (const float4*)(in + (size_t)b0 * 256);
  float4* s4 = (float4*)in_s;
#pragma unroll
  for (int i = 0; i < 2; ++i) s4[i * 256 + tid] = in4[i * 256 + tid];
  __syncthreads();

  float4 acc0 = {0.f, 0.f, 0.f, 0.f};
  float4 acc1 = {0.f, 0.f, 0.f, 0.f};
  for (int k4 = 0; k4 < 64; ++k4) {
    const float4 w0 = ((const float4*)(W + (k4 * 4 + 0) * 256))[jq];
    const float4 w1 = ((const float4*)(W + (k4 * 4 + 1) * 256))[jq];
    const float4 w2 = ((const float4*)(W + (k4 * 4 + 2) * 256))[jq];
    const float4 w3 = ((const float4*)(W + (k4 * 4 + 3) * 256))[jq];
    const float4 v0 = ((const float4*)(in_s + (r0 + 0) * 256))[k4];  // broadcast
    const float4 v1 = ((const float4*)(in_s + (r0 + 1) * 256))[k4];  // broadcast
    acc0.x = fmaf(v0.x, w0.x, fmaf(v0.y, w1.x, fmaf(v0.z, w2.x, fmaf(v0.w, w3.x, acc0.x))));
    acc0.y = fmaf(v0.x, w0.y, fmaf(v0.y, w1.y, fmaf(v0.z, w2.y, fmaf(v0.w, w3.y, acc0.y))));
    acc0.z = fmaf(v0.x, w0.z, fmaf(v0.y, w1.z, fmaf(v0.z, w2.z, fmaf(v0.w, w3.z, acc0.z))));
    acc0.w = fmaf(v0.x, w0.w, fmaf(v0.y, w1.w, fmaf(v0.z, w2.w, fmaf(v0.w, w3.w, acc0.w))));
    acc1.x = fmaf(v1.x, w0.x, fmaf(v1.y, w1.x, fmaf(v1.z, w2.x, fmaf(v1.w, w3.x, acc1.x))));
    acc1.y = fmaf(v1.x, w0.y, fmaf(v1.y, w1.y, fmaf(v1.z, w2.y, fmaf(v1.w, w3.y, acc1.y))));
    acc1.z = fmaf(v1.x, w0.z, fmaf(v1.y, w1.z, fmaf(v1.z, w2.z, fmaf(v1.w, w3.z, acc1.z))));
    acc1.w = fmaf(v1.x, w0.w, fmaf(v1.y, w1.w, fmaf(v1.z, w2.w, fmaf(v1.w, w3.w, acc1.w))));
  }
  ((float4*)(out + (size_t)(b0 + r0 + 0) * 256))[jq] = acc0;
  ((float4*)(out + (size_t)(b0 + r0 + 1) * 256))[jq] = acc1;
}

// ---------------- fused per-b: DMA-stage opp[b] -> scores -> softmax*hard -> v
__global__ __launch_bounds__(256, 2) void fused_kernel(
    const float* __restrict__ opp, const float* __restrict__ T,
    const float* __restrict__ hard, float* __restrict__ scores_out,
    float* __restrict__ V) {
  __shared__ float opp_s[Nn * Ll];  // 64 KB
  __shared__ float sraw[Nn];
  __shared__ float sfin[Nn];

  const int b = blockIdx.x;
  const int tid = threadIdx.x;
  const int lane = tid & 63;
  const int wave = tid >> 6;

  // DMA stage opp[b] (64 KB): wave-uniform LDS base + lane*16 scatter.
  const float4* o4 = (const float4*)(opp + (size_t)b * (Nn * Ll));
  float4* os4 = (float4*)opp_s;
#pragma unroll
  for (int i = 0; i < 16; ++i)
    gload_lds16(o4 + i * 256 + wave * 64 + lane, os4 + i * 256 + wave * 64);

  // t fragment straight from global (1 KB coalesced, identical across waves -> L1)
  const float4 tv = ((const float4*)(T + (size_t)b * Ll))[lane];
  __syncthreads();  // drains vmcnt (DMA) before LDS reads

  // scores: wave w handles n = w*16..w*16+15; 64-lane dot over l.
  for (int jj = 0; jj < 16; ++jj) {
    const int n = wave * 16 + jj;
    const float4 ov = ((const float4*)(opp_s + n * Ll))[lane];
    float p = ov.x * tv.x + ov.y * tv.y + ov.z * tv.z + ov.w * tv.w;
#pragma unroll
    for (int off = 32; off; off >>= 1) p += __shfl_down(p, off, 64);
    if (lane == 0) sraw[n] = p;
  }
  __syncthreads();

  // softmax over n (64 values) * hard_attention, one wave
  if (tid < 64) {
    const float x = sraw[tid];
    float m = x;
#pragma unroll
    for (int off = 32; off; off >>= 1) m = fmaxf(m, __shfl_xor(m, off, 64));
    const float e = __expf(x - m);
    float s = e;
#pragma unroll
    for (int off = 32; off; off >>= 1) s += __shfl_xor(s, off, 64);
    const float val = e / s * hard[(size_t)b * Nn + tid];
    sfin[tid] = val;
    scores_out[(size_t)b * Nn + tid] = val;
  }
  __syncthreads();

  // v[b,l]: thread l = tid; 64 conflict-free b32 reads (2 lanes/bank = free),
  // sfin[n] broadcast. No extra barrier needed.
  float acc = 0.f;
#pragma unroll
  for (int n = 0; n < Nn; ++n) acc = fmaf(sfin[n], opp_s[n * Ll + tid], acc);
  V[(size_t)b * Ll + tid] = acc;
}

extern "C" void kernel_launch(void* const* d_in, const int* in_sizes, int n_in,
                              void* d_out, int out_size, void* d_ws, size_t ws_size,
                              hipStream_t stream) {
  const float* agent = (const float*)d_in[0];
  const float* opp   = (const float*)d_in[1];
  const float* hard  = (const float*)d_in[2];
  const float* Ws    = (const float*)d_in[3];
  const float* Wt    = (const float*)d_in[4];
  const float* Wc    = (const float*)d_in[5];

  float* out = (float*)d_out;                  // result [B,E]
  float* scores_out = out + (size_t)Bsz * Ee;  // scores [B,N]

  float* ws  = (float*)d_ws;
  float* MT  = ws;                     // 65536
  float* WcT = MT + 65536;             // 65536
  float* T   = WcT + 65536;            // B*L
  float* V   = T + (size_t)Bsz * Ll;   // B*L

  prep_kernel<<<512, 256, 0, stream>>>(Ws, Wt, Wc, MT, WcT);
  rowmat_kernel<<<dim3(Bsz / 8, 1), 256, 0, stream>>>(agent, MT, T);   // T = agent @ M.T
  fused_kernel<<<Bsz, 256, 0, stream>>>(opp, T, hard, scores_out, V);
  rowmat_kernel<<<dim3(Bsz / 8, 1), 256, 0, stream>>>(V, WcT, out);    // result = V @ Wc.T
}

// Round 4
// 420.159 us; speedup vs baseline: 1.0854x; 1.0539x over previous
//
#include <hip/hip_runtime.h>

// Problem: B=4096, N=64, L=256, E=256, all fp32.
// d_in: 0=agent[B,L] 1=opp[B,N,L] 2=hard[B,N] 3=Ws[E,L] 4=Wt[E,L] 5=Wc[E,L]
// d_out: result[B,E] (1048576 f32) then scores[B,N] (262144 f32)
//
// Algebra: scores[b,n] = opp[b,n,:] @ M @ agent[b,:],  M[l,l'] = sum_e Wt[e,l]*Ws[e,l']
//          result[b,e] = sum_l Wc[e,l] * v[b,l],       v[b,l] = sum_n s[b,n]*opp[b,n,l]
// Mega-kernel: block owns 8 b's. Prologue computes T rows (agent@M.T) in-block,
// main loop streams opp[b] (DMA->LDS, read exactly once), epilogue does V@Wc.T
// from LDS-resident V_s. opp 256 MB streamed once => ~43 us HBM floor; T and V
// never touch HBM. Timed window carries ~330 us of harness resets/readback.

#define Bsz 4096
#define Nn  64
#define Ll  256
#define Ee  256

__device__ __forceinline__ void gload_lds16(const float4* g, float4* lds_base) {
  __builtin_amdgcn_global_load_lds(
      (const __attribute__((address_space(1))) unsigned int*)g,
      (__attribute__((address_space(3))) unsigned int*)lds_base,
      16, 0, 0);
}

// ---------------- prep: MT[k][j] = M[j,k] = sum_e Ws[e,k]*Wt[e,j] ; WcT[l][e] = Wc[e,l]
__global__ __launch_bounds__(256) void prep_kernel(
    const float* __restrict__ Ws, const float* __restrict__ Wt,
    const float* __restrict__ Wc, float* __restrict__ MT, float* __restrict__ WcT) {
  int col = threadIdx.x;
  int row = blockIdx.x;
  if (row < 256) {
    float acc = 0.f;
    for (int e = 0; e < 256; ++e)
      acc = fmaf(Ws[e * 256 + row], Wt[e * 256 + col], acc);  // Ws uniform/blk, Wt coalesced
    MT[row * 256 + col] = acc;
  } else {
    int l = row - 256;
    WcT[l * 256 + col] = Wc[col * 256 + l];
  }
}

// ---------------- mega: per block, 8 b's end-to-end.
// LDS: opp_s 64K + V_s 8K + sraw/sfin 0.5K = 72.5K -> 2 blocks/CU.
__global__ __launch_bounds__(256, 2) void mega_kernel(
    const float* __restrict__ agent, const float* __restrict__ opp,
    const float* __restrict__ hard, const float* __restrict__ MT,
    const float* __restrict__ WcT, float* __restrict__ out,
    float* __restrict__ scores_out) {
  __shared__ float opp_s[Nn * Ll];   // 64 KB; first 16 KB aliased by prologue
  __shared__ float V_s[8 * Ll];      // 8 KB
  __shared__ float sraw[Nn];
  __shared__ float sfin[Nn];

  const int tid = threadIdx.x;
  const int lane = tid & 63;
  const int wave = tid >> 6;
  const int b0 = blockIdx.x * 8;

  const int jq = lane;        // j = 4*jq .. 4*jq+3 (rowmat pattern)
  const int r0 = wave * 2;    // 2 local rows per wave-group

  // ======== prologue: T[r][j] = sum_k agent[b0+r][k] * MT[k*256+j], r=0..7
  float* ag_s  = opp_s;          // [8][256] = 8 KB
  float* T_tmp = opp_s + 2048;   // [8][256] = 8 KB
  {
    const float4* in4 = (const float4*)(agent + (size_t)b0 * 256);
    float4* s4 = (float4*)ag_s;
    s4[tid] = in4[tid];
    s4[256 + tid] = in4[256 + tid];
    __syncthreads();

    float4 a0 = {0.f, 0.f, 0.f, 0.f};
    float4 a1 = {0.f, 0.f, 0.f, 0.f};
    for (int k4 = 0; k4 < 64; ++k4) {
      const float4 w0 = ((const float4*)(MT + (k4 * 4 + 0) * 256))[jq];
      const float4 w1 = ((const float4*)(MT + (k4 * 4 + 1) * 256))[jq];
      const float4 w2 = ((const float4*)(MT + (k4 * 4 + 2) * 256))[jq];
      const float4 w3 = ((const float4*)(MT + (k4 * 4 + 3) * 256))[jq];
      const float4 v0 = ((const float4*)(ag_s + (r0 + 0) * 256))[k4];
      const float4 v1 = ((const float4*)(ag_s + (r0 + 1) * 256))[k4];
      a0.x = fmaf(v0.x, w0.x, fmaf(v0.y, w1.x, fmaf(v0.z, w2.x, fmaf(v0.w, w3.x, a0.x))));
      a0.y = fmaf(v0.x, w0.y, fmaf(v0.y, w1.y, fmaf(v0.z, w2.y, fmaf(v0.w, w3.y, a0.y))));
      a0.z = fmaf(v0.x, w0.z, fmaf(v0.y, w1.z, fmaf(v0.z, w2.z, fmaf(v0.w, w3.z, a0.z))));
      a0.w = fmaf(v0.x, w0.w, fmaf(v0.y, w1.w, fmaf(v0.z, w2.w, fmaf(v0.w, w3.w, a0.w))));
      a1.x = fmaf(v1.x, w0.x, fmaf(v1.y, w1.x, fmaf(v1.z, w2.x, fmaf(v1.w, w3.x, a1.x))));
      a1.y = fmaf(v1.x, w0.y, fmaf(v1.y, w1.y, fmaf(v1.z, w2.y, fmaf(v1.w, w3.y, a1.y))));
      a1.z = fmaf(v1.x, w0.z, fmaf(v1.y, w1.z, fmaf(v1.z, w2.z, fmaf(v1.w, w3.z, a1.z))));
      a1.w = fmaf(v1.x, w0.w, fmaf(v1.y, w1.w, fmaf(v1.z, w2.w, fmaf(v1.w, w3.w, a1.w))));
    }
    __syncthreads();  // ag_s reads done before T_tmp writes overlap region? (disjoint, but cheap)
    ((float4*)(T_tmp + (r0 + 0) * 256))[jq] = a0;
    ((float4*)(T_tmp + (r0 + 1) * 256))[jq] = a1;
    __syncthreads();
  }
  // pull tv[i] = T[b0+i][lane*4 .. +3] into registers, then free the region
  float4 tv[8];
#pragma unroll
  for (int i = 0; i < 8; ++i) tv[i] = ((const float4*)(T_tmp + i * 256))[lane];
  __syncthreads();  // all reads done before DMA overwrites opp_s

  // ======== main loop over 8 b's
  const float4* o4base = (const float4*)(opp + (size_t)b0 * (Nn * Ll));
  float4* os4 = (float4*)opp_s;
#pragma unroll
  for (int i = 0; i < 8; ++i) {
    const float4* o4 = o4base + (size_t)i * 4096;
    // DMA stage opp[b0+i] (64 KB): wave-uniform LDS base + lane*16 scatter
#pragma unroll
    for (int k = 0; k < 16; ++k)
      gload_lds16(o4 + k * 256 + wave * 64 + lane, os4 + k * 256 + wave * 64);
    __syncthreads();  // drain DMA

    // scores: wave w -> n = 16w..16w+15; 64-lane dot over l
    const float4 tvi = tv[i];
    for (int jj = 0; jj < 16; ++jj) {
      const int n = wave * 16 + jj;
      const float4 ov = ((const float4*)(opp_s + n * Ll))[lane];
      float p = ov.x * tvi.x + ov.y * tvi.y + ov.z * tvi.z + ov.w * tvi.w;
#pragma unroll
      for (int off = 32; off; off >>= 1) p += __shfl_down(p, off, 64);
      if (lane == 0) sraw[n] = p;
    }
    __syncthreads();

    // softmax * hard (one wave)
    if (tid < 64) {
      const float x = sraw[tid];
      float m = x;
#pragma unroll
      for (int off = 32; off; off >>= 1) m = fmaxf(m, __shfl_xor(m, off, 64));
      const float e = __expf(x - m);
      float s = e;
#pragma unroll
      for (int off = 32; off; off >>= 1) s += __shfl_xor(s, off, 64);
      const float val = e / s * hard[(size_t)(b0 + i) * Nn + tid];
      sfin[tid] = val;
      scores_out[(size_t)(b0 + i) * Nn + tid] = val;
    }
    __syncthreads();

    // v[b,l] -> V_s: thread l = tid; conflict-free b32 (2 lanes/bank), sfin broadcast
    float acc = 0.f;
#pragma unroll
    for (int n = 0; n < Nn; ++n) acc = fmaf(sfin[n], opp_s[n * Ll + tid], acc);
    V_s[i * Ll + tid] = acc;
    __syncthreads();  // opp_s reads done before next iter's DMA; V_s visible at end
  }

  // ======== epilogue: out[b0+r][j] = sum_l V_s[r][l] * WcT[l*256+j]
  {
    float4 a0 = {0.f, 0.f, 0.f, 0.f};
    float4 a1 = {0.f, 0.f, 0.f, 0.f};
    for (int k4 = 0; k4 < 64; ++k4) {
      const float4 w0 = ((const float4*)(WcT + (k4 * 4 + 0) * 256))[jq];
      const float4 w1 = ((const float4*)(WcT + (k4 * 4 + 1) * 256))[jq];
      const float4 w2 = ((const float4*)(WcT + (k4 * 4 + 2) * 256))[jq];
      const float4 w3 = ((const float4*)(WcT + (k4 * 4 + 3) * 256))[jq];
      const float4 v0 = ((const float4*)(V_s + (r0 + 0) * 256))[k4];
      const float4 v1 = ((const float4*)(V_s + (r0 + 1) * 256))[k4];
      a0.x = fmaf(v0.x, w0.x, fmaf(v0.y, w1.x, fmaf(v0.z, w2.x, fmaf(v0.w, w3.x, a0.x))));
      a0.y = fmaf(v0.x, w0.y, fmaf(v0.y, w1.y, fmaf(v0.z, w2.y, fmaf(v0.w, w3.y, a0.y))));
      a0.z = fmaf(v0.x, w0.z, fmaf(v0.y, w1.z, fmaf(v0.z, w2.z, fmaf(v0.w, w3.z, a0.z))));
      a0.w = fmaf(v0.x, w0.w, fmaf(v0.y, w1.w, fmaf(v0.z, w2.w, fmaf(v0.w, w3.w, a0.w))));
      a1.x = fmaf(v1.x, w0.x, fmaf(v1.y, w1.x, fmaf(v1.z, w2.x, fmaf(v1.w, w3.x, a1.x))));
      a1.y = fmaf(v1.x, w0.y, fmaf(v1.y, w1.y, fmaf(v1.z, w2.y, fmaf(v1.w, w3.y, a1.y))));
      a1.z = fmaf(v1.x, w0.z, fmaf(v1.y, w1.z, fmaf(v1.z, w2.z, fmaf(v1.w, w3.z, a1.z))));
      a1.w = fmaf(v1.x, w0.w, fmaf(v1.y, w1.w, fmaf(v1.z, w2.w, fmaf(v1.w, w3.w, a1.w))));
    }
    ((float4*)(out + (size_t)(b0 + r0 + 0) * 256))[jq] = a0;
    ((float4*)(out + (size_t)(b0 + r0 + 1) * 256))[jq] = a1;
  }
}

extern "C" void kernel_launch(void* const* d_in, const int* in_sizes, int n_in,
                              void* d_out, int out_size, void* d_ws, size_t ws_size,
                              hipStream_t stream) {
  const float* agent = (const float*)d_in[0];
  const float* opp   = (const float*)d_in[1];
  const float* hard  = (const float*)d_in[2];
  const float* Ws    = (const float*)d_in[3];
  const float* Wt    = (const float*)d_in[4];
  const float* Wc    = (const float*)d_in[5];

  float* out = (float*)d_out;                  // result [B,E]
  float* scores_out = out + (size_t)Bsz * Ee;  // scores [B,N]

  float* ws  = (float*)d_ws;
  float* MT  = ws;             // 65536 floats
  float* WcT = MT + 65536;     // 65536 floats

  prep_kernel<<<512, 256, 0, stream>>>(Ws, Wt, Wc, MT, WcT);
  mega_kernel<<<Bsz / 8, 256, 0, stream>>>(agent, opp, hard, MT, WcT, out, scores_out);
}